// Round 18
// baseline (308.848 us; speedup 1.0000x reference)
//
#include <hip/hip_runtime.h>

typedef __attribute__((ext_vector_type(4))) float f32x4;
typedef __attribute__((ext_vector_type(8))) short bf16x8;

#define AS1 __attribute__((address_space(1)))
#define AS3 __attribute__((address_space(3)))

static __device__ __forceinline__ ushort f2b(float f) {
    uint u = __float_as_uint(f);
    uint r = (u + 0x7fffu + ((u >> 16) & 1u)) >> 16;
    return (ushort)r;
}
static __device__ __forceinline__ float b2f(ushort h) {
    return __uint_as_float(((uint)h) << 16);
}

// ---------------- fp32 -> bf16 convert (vectorized, grid-stride) -------------
__global__ __launch_bounds__(256) void f2b_kernel(const float* __restrict__ in,
                                                  ushort* __restrict__ out, int n4) {
    int i = blockIdx.x * blockDim.x + threadIdx.x;
    int stride = gridDim.x * blockDim.x;
    for (; i < n4; i += stride) {
        float4 v = ((const float4*)in)[i];
        ushort4 o;
        o.x = f2b(v.x); o.y = f2b(v.y); o.z = f2b(v.z); o.w = f2b(v.w);
        ((ushort4*)out)[i] = o;
    }
}

// ---- three equally-sized fp32 arrays -> one contiguous bf16 output ---------
__global__ __launch_bounds__(256) void f2b3_kernel(const float* __restrict__ A,
                                                   const float* __restrict__ B,
                                                   const float* __restrict__ C,
                                                   ushort* __restrict__ out, int n4) {
    int i = blockIdx.x * blockDim.x + threadIdx.x;
    int stride = gridDim.x * blockDim.x;
    for (; i < 3 * n4; i += stride) {
        const float* src = (i < n4) ? A : ((i < 2 * n4) ? B : C);
        int j = (i < n4) ? i : ((i < 2 * n4) ? i - n4 : i - 2 * n4);
        float4 v = ((const float4*)src)[j];
        ushort4 o;
        o.x = f2b(v.x); o.y = f2b(v.y); o.z = f2b(v.z); o.w = f2b(v.w);
        ((ushort4*)out)[i] = o;
    }
}

// ============ bf16 GEMM, C = A * B^T, 128x256 tile, BK=32, ring-3 ===========
// OCCUPANCY EXPERIMENT: acc = 64 f32/thread (wave-tile 64x64), combined
// regs <= 128 via __launch_bounds__(512,4) -> 2 blocks/CU (16 waves).
// Inter-block TLP covers barrier/vmcnt drains (m114/m97 mechanism).
// LDS: ring-3 x (A 8K + B 16K) = 72 KiB; stage kt+2 during kt (2-tile lead);
// counted vmcnt(3) seal per tile. Slot swizzle: slot = logical ^ (row&3).
// mode 0 = Q (C write), 1 = K (C write + row sum-sq atomics -> rnorm),
// 2 = V (no C write; fused sum_n K*V/||K|| -> gf from accumulators).
#define PIN_PRE()  do { __builtin_amdgcn_s_barrier(); \
                        asm volatile("s_waitcnt lgkmcnt(0)" ::: "memory"); \
                        __builtin_amdgcn_s_setprio(1); } while (0)
#define PIN_POST() do { __builtin_amdgcn_s_setprio(0); \
                        __builtin_amdgcn_s_barrier(); } while (0)

__device__ __forceinline__ void stage_tile(const ushort* __restrict__ A,
                                           const ushort* __restrict__ Bw,
                                           ushort* As, ushort* Bs, int sl,
                                           int row0, int col0, int kcol,
                                           int t, int w) {
    // A: 128x32 = 512 chunks (1 instr); B: 256x32 = 1024 chunks (2 instr)
    {
        int c = t;
        int r = c >> 2, s = (c & 3) ^ (r & 3);
        const ushort* src = A + (size_t)(row0 + r) * 1024 + kcol + s * 8;
        ushort* dst = As + sl * 4096 + w * 512;  // wave-uniform + lane*16B
        __builtin_amdgcn_global_load_lds((const AS1 void*)src, (AS3 void*)dst, 16, 0, 0);
    }
#pragma unroll
    for (int i = 0; i < 2; ++i) {
        int c = i * 512 + t;
        int r = c >> 2, s = (c & 3) ^ (r & 3);
        const ushort* src = Bw + (size_t)(col0 + r) * 1024 + kcol + s * 8;
        ushort* dst = Bs + sl * 8192 + i * 4096 + w * 512;
        __builtin_amdgcn_global_load_lds((const AS1 void*)src, (AS3 void*)dst, 16, 0, 0);
    }
}

__global__ __launch_bounds__(512, 4) void gemm_bt(const ushort* __restrict__ A,
                                                  const ushort* __restrict__ Bw,
                                                  ushort* __restrict__ C,
                                                  float* __restrict__ rnorm,
                                                  float* __restrict__ gf,
                                                  int mode) {
    __shared__ ushort SMEM[36864];           // 72 KiB: As 3x8K | Bs 3x16K
    ushort* As = SMEM;                       // [3][4096]
    ushort* Bs = SMEM + 12288;               // [3][8192]

    // T1: XCD-chunked swizzle (nwg = 1024)
    int nwg = gridDim.x, cpx = nwg >> 3, bid = blockIdx.x;
    int orig = (bid & 7) * cpx + (bid >> 3);
    int rt = orig >> 2, ct = orig & 3;       // 256 row-tiles x 4 col-tiles
    int row0 = rt * 128, col0 = ct * 256;

    int t = threadIdx.x, l = t & 63, w = t >> 6;
    int wr = w >> 2, wc = w & 3;             // wave grid 2(M) x 4(N), out 64x64
    int lr = l & 15, c16 = l >> 4;

    int rslot = (c16 ^ (lr & 3)) << 4;       // read slot bytes within 64B row

    f32x4 acc[4][4] = {};                    // 64 f32/thread
    bf16x8 a[4], b[4];

    const int NT = 32;  // K=1024 / 32
    stage_tile(A, Bw, As, Bs, 0, row0, col0, 0, t, w);
    stage_tile(A, Bw, As, Bs, 1, row0, col0, 32, t, w);
    asm volatile("s_waitcnt vmcnt(3)" ::: "memory");   // seal tile 0
    __builtin_amdgcn_s_barrier();

    for (int kt = 0; kt < NT; ++kt) {
        int sl = kt % 3;
        const char* Ab = (const char*)As + sl * 8192;
        const char* Bb = (const char*)Bs + sl * 16384;

#pragma unroll
        for (int mf = 0; mf < 4; ++mf)
            a[mf] = *(const bf16x8*)(Ab + (wr * 64 + mf * 16 + lr) * 64 + rslot);
#pragma unroll
        for (int nf = 0; nf < 4; ++nf)
            b[nf] = *(const bf16x8*)(Bb + (wc * 64 + nf * 16 + lr) * 64 + rslot);
        if (kt + 2 < NT)
            stage_tile(A, Bw, As, Bs, (kt + 2) % 3, row0, col0, (kt + 2) * 32, t, w);
        PIN_PRE();
#pragma unroll
        for (int mf = 0; mf < 4; ++mf)
#pragma unroll
            for (int nf = 0; nf < 4; ++nf)
                acc[mf][nf] = __builtin_amdgcn_mfma_f32_16x16x32_bf16(a[mf], b[nf], acc[mf][nf], 0, 0, 0);
        __builtin_amdgcn_s_setprio(0);
        // seal tile kt+1 before its reads next iteration
        if (kt + 2 < NT)      asm volatile("s_waitcnt vmcnt(3)" ::: "memory");
        else if (kt + 1 < NT) asm volatile("s_waitcnt vmcnt(0)" ::: "memory");
        __builtin_amdgcn_s_barrier();
    }

    // ---- mode 1: per-row sum-of-squares -> rnorm atomics (fp32 acc) --------
    if (mode == 1) {
#pragma unroll
        for (int mf = 0; mf < 4; ++mf)
#pragma unroll
            for (int j = 0; j < 4; ++j) {
                float s = acc[mf][0][j] * acc[mf][0][j] + acc[mf][1][j] * acc[mf][1][j]
                        + acc[mf][2][j] * acc[mf][2][j] + acc[mf][3][j] * acc[mf][3][j];
                s += __shfl_xor(s, 1); s += __shfl_xor(s, 2);
                s += __shfl_xor(s, 4); s += __shfl_xor(s, 8);
                if (lr == 0)
                    atomicAdd(&rnorm[row0 + wr * 64 + mf * 16 + c16 * 4 + j], s);
            }
    }

    if (mode != 2) {
        // ---- C tile (128x256) -> SMEM (64 KiB), coalesced 16B stores -------
        __syncthreads();
#pragma unroll
        for (int mf = 0; mf < 4; ++mf) {
            int lrow = wr * 64 + mf * 16 + c16 * 4;
#pragma unroll
            for (int nf = 0; nf < 4; ++nf) {
                int lcol = wc * 64 + nf * 16 + lr;
#pragma unroll
                for (int j = 0; j < 4; ++j)
                    SMEM[(lrow + j) * 256 + lcol] = f2b(acc[mf][nf][j]);
            }
        }
        __syncthreads();
#pragma unroll
        for (int g = 0; g < 8; ++g) {
            int ch = g * 512 + t;            // 16B chunks of the 128x256 tile
            int r = ch >> 5, c8 = ch & 31;
            bf16x8 v = *(const bf16x8*)&SMEM[ch * 8];
            *(bf16x8*)&C[(size_t)(row0 + r) * 1024 + col0 + c8 * 8] = v;
        }
    } else {
        // ---- mode 2: register-sourced fused gf reduce ----------------------
        float p[4] = {0.f, 0.f, 0.f, 0.f};
#pragma unroll
        for (int mf = 0; mf < 4; ++mf)
#pragma unroll
            for (int j = 0; j < 4; ++j) {
                int row_t = wr * 64 + mf * 16 + c16 * 4 + j;
                float inv = 1.0f / fmaxf(sqrtf(rnorm[row0 + row_t]), 1e-12f);
                const ushort* krow = &C[(size_t)(row0 + row_t) * 1024 + col0];
#pragma unroll
                for (int nf = 0; nf < 4; ++nf)
                    p[nf] += b2f(krow[wc * 64 + nf * 16 + lr]) * inv * acc[mf][nf][j];
            }
#pragma unroll
        for (int nf = 0; nf < 4; ++nf) {
            p[nf] += __shfl_xor(p[nf], 16);
            p[nf] += __shfl_xor(p[nf], 32);
        }
        __syncthreads();
        float* part = (float*)SMEM;          // [8 waves][4 nf][16 lr] = 2 KiB
        if (l < 16) {
#pragma unroll
            for (int nf = 0; nf < 4; ++nf) part[(w * 4 + nf) * 16 + lr] = p[nf];
        }
        __syncthreads();
        if (t < 256) {
            // col c = wc*64 + nf*16 + lr
            int wcq = t >> 6, nq = (t >> 4) & 3, lq = t & 15;
            float s = part[((wcq) * 4 + nq) * 16 + lq]
                    + part[((4 + wcq) * 4 + nq) * 16 + lq];
            int b = row0 >> 12;
            atomicAdd(&gf[b * 1024 + col0 + t], s * (1.0f / 4096.0f));
        }
    }
}

// ---------------- out[row,e] = l2norm(Q_pre)[row,e] * gf[b,e]  (fp32 out) ---
__global__ __launch_bounds__(256) void q_scale(const ushort* __restrict__ Qp,
                                               const float* __restrict__ gf,
                                               float* __restrict__ out) {
    const int D = 1024;
    int row = blockIdx.x * 4 + (threadIdx.x >> 6);
    int l = threadIdx.x & 63;
    int b = row >> 12;
    const ushort* qr = &Qp[(size_t)row * D];
    float qf[4][4];
    float ss = 0.f;
#pragma unroll
    for (int i = 0; i < 4; ++i) {
        ushort4 q = *(const ushort4*)&qr[l * 4 + i * 256];
        qf[i][0] = b2f(q.x); qf[i][1] = b2f(q.y);
        qf[i][2] = b2f(q.z); qf[i][3] = b2f(q.w);
        ss += qf[i][0] * qf[i][0] + qf[i][1] * qf[i][1] +
              qf[i][2] * qf[i][2] + qf[i][3] * qf[i][3];
    }
#pragma unroll
    for (int off = 32; off; off >>= 1) ss += __shfl_xor(ss, off);
    float inv = 1.0f / fmaxf(sqrtf(ss), 1e-12f);
#pragma unroll
    for (int i = 0; i < 4; ++i) {
        float4 g = *(const float4*)&gf[b * D + l * 4 + i * 256];
        float4 o;
        o.x = qf[i][0] * inv * g.x;
        o.y = qf[i][1] * inv * g.y;
        o.z = qf[i][2] * inv * g.z;
        o.w = qf[i][3] * inv * g.w;
        *(float4*)&out[(size_t)row * D + l * 4 + i * 256] = o;
    }
}

extern "C" void kernel_launch(void* const* d_in, const int* in_sizes, int n_in,
                              void* d_out, int out_size, void* d_ws, size_t ws_size,
                              hipStream_t stream) {
    const float* x  = (const float*)d_in[0];
    const float* Wq = (const float*)d_in[1];
    const float* Wk = (const float*)d_in[2];
    const float* Wv = (const float*)d_in[3];
    float* out = (float*)d_out;

    const int Bb = 8, Nn = 4096, D = 1024;
    const int M = Bb * Nn;  // 32768 rows

    char* ws = (char*)d_ws;
    ushort* xb  = (ushort*)ws;                         // 67108864 B (bf16 x)
    ushort* wqb = (ushort*)(ws + 67108864);            // 2097152 B  } contiguous
    ushort* wkb = (ushort*)(ws + 69206016);            // 2097152 B  } bf16 W's
    ushort* wvb = (ushort*)(ws + 71303168);            // 2097152 B  }
    ushort* P1  = (ushort*)(ws + 73400320);            // 67108864 B (Q_pre)
    float*  gf  = (float*)(ws + 140509184);            // 32768 B

    // d_out scratch: [Kp bf16 64MB][rnorm 128KB] — dead before q_scale writes.
    ushort* Kp = (ushort*)d_out;
    float* rnorm = (float*)((char*)d_out + 67108864);

    hipMemsetAsync(gf, 0, Bb * D * sizeof(float), stream);
    hipMemsetAsync(rnorm, 0, M * sizeof(float), stream);

    f2b_kernel<<<2048, 256, 0, stream>>>(x, xb, (M * D) / 4);
    f2b3_kernel<<<1536, 256, 0, stream>>>(Wq, Wk, Wv, wqb, (D * D) / 4);

    gemm_bt<<<1024, 512, 0, stream>>>(xb, wkb, Kp, rnorm, nullptr, 1);   // K
    gemm_bt<<<1024, 512, 0, stream>>>(xb, wvb, Kp, rnorm, gf, 2);        // V->gf
    gemm_bt<<<1024, 512, 0, stream>>>(xb, wqb, P1, nullptr, nullptr, 0); // Q
    q_scale<<<M / 4, 256, 0, stream>>>(P1, gf, out);
}

// Round 19
// 283.389 us; speedup vs baseline: 1.0898x; 1.0898x over previous
//
#include <hip/hip_runtime.h>

typedef __attribute__((ext_vector_type(4))) float f32x4;
typedef __attribute__((ext_vector_type(8))) short bf16x8;

#define AS1 __attribute__((address_space(1)))
#define AS3 __attribute__((address_space(3)))

static __device__ __forceinline__ ushort f2b(float f) {
    uint u = __float_as_uint(f);
    uint r = (u + 0x7fffu + ((u >> 16) & 1u)) >> 16;
    return (ushort)r;
}
static __device__ __forceinline__ float b2f(ushort h) {
    return __uint_as_float(((uint)h) << 16);
}

// ---------------- fp32 -> bf16 convert (vectorized, grid-stride) -------------
__global__ __launch_bounds__(256) void f2b_kernel(const float* __restrict__ in,
                                                  ushort* __restrict__ out, int n4) {
    int i = blockIdx.x * blockDim.x + threadIdx.x;
    int stride = gridDim.x * blockDim.x;
    for (; i < n4; i += stride) {
        float4 v = ((const float4*)in)[i];
        ushort4 o;
        o.x = f2b(v.x); o.y = f2b(v.y); o.z = f2b(v.z); o.w = f2b(v.w);
        ((ushort4*)out)[i] = o;
    }
}

// ---- three equally-sized fp32 arrays -> one contiguous bf16 output ---------
__global__ __launch_bounds__(256) void f2b3_kernel(const float* __restrict__ A,
                                                   const float* __restrict__ B,
                                                   const float* __restrict__ C,
                                                   ushort* __restrict__ out, int n4) {
    int i = blockIdx.x * blockDim.x + threadIdx.x;
    int stride = gridDim.x * blockDim.x;
    for (; i < 3 * n4; i += stride) {
        const float* src = (i < n4) ? A : ((i < 2 * n4) ? B : C);
        int j = (i < n4) ? i : ((i < 2 * n4) ? i - n4 : i - 2 * n4);
        float4 v = ((const float4*)src)[j];
        ushort4 o;
        o.x = f2b(v.x); o.y = f2b(v.y); o.z = f2b(v.z); o.w = f2b(v.w);
        ((ushort4*)out)[i] = o;
    }
}

// ---------------- bf16 GEMM, C = A * B^T, 256x256, BK=64, 4-phase ----------
// R13's proven schedule. SMEM held at EXACTLY 128 KiB (R14 lesson: >128 KiB
// LDS allocation cost ~17% on the whole K-loop). MODE: 0 = Q (plain C write),
// 1 = K (C write + per-row sum-of-squares atomics into rnorm), 2 = V
// (no C write; fused sum_n K*V/||K|| -> gf, V taken from fp32 accumulators,
// K re-read from global (L3), cross-wave combine in 2 KiB of the freed SMEM).
__device__ __forceinline__ void stage_q(const ushort* __restrict__ G,
                                        ushort* Ls, int buf, int q, int rc0,
                                        int kcol, int w, int srow, int schunk) {
    ushort* dst = Ls + (buf * 4 + q) * 4096 + w * 512;  // wave-uniform base
    const ushort* src = G + (size_t)(rc0 + q * 64 + srow) * 1024 + kcol + schunk * 8;
    __builtin_amdgcn_global_load_lds((const AS1 void*)src, (AS3 void*)dst, 16, 0, 0);
}

#define PIN_PRE()  do { __builtin_amdgcn_s_barrier(); \
                        asm volatile("s_waitcnt lgkmcnt(0)" ::: "memory"); \
                        __builtin_amdgcn_s_setprio(1); } while (0)
#define PIN_POST() do { __builtin_amdgcn_s_setprio(0); \
                        __builtin_amdgcn_s_barrier(); } while (0)

template <int MODE>
__global__ __launch_bounds__(512, 2) void gemm_bt(const ushort* __restrict__ A,
                                                  const ushort* __restrict__ Bw,
                                                  ushort* __restrict__ C,
                                                  float* __restrict__ rnorm,
                                                  float* __restrict__ gf) {
    __shared__ ushort SMEM[65536];   // 128 KiB exactly: As | Bs
    ushort* As = SMEM;
    ushort* Bs = SMEM + 32768;

    // T1: XCD-chunked swizzle (nwg = 512)
    int nwg = gridDim.x, cpx = nwg >> 3, bid = blockIdx.x;
    int orig = (bid & 7) * cpx + (bid >> 3);
    int rt = orig >> 2, ct = orig & 3;
    int row0 = rt * 256, col0 = ct * 256;

    int t = threadIdx.x, l = t & 63, w = t >> 6;
    int wr = w >> 2, wc = w & 3;     // wave grid 2 (M) x 4 (N)
    int lr = l & 15, c16 = l >> 4;

    int srow = t >> 3;                     // staging row within quarter
    int schunk = (l & 7) ^ ((l >> 3) & 7); // staging source 16B chunk
    int o0 = ((c16 ^ (l & 7))) * 16;       // read slot bytes, k=0
    int o1 = o0 ^ 64;                      // k=1

    f32x4 acc[8][4] = {};
    bf16x8 a[4], a2[4], blo[2][2], bhi[2][2];

    const int NT = 16;  // K=1024 / 64
    // prologue: buf0 all 8 quarters; buf1: A-even (q0,q2) + B q0-3
#pragma unroll
    for (int q = 0; q < 4; ++q) stage_q(Bw, Bs, 0, q, col0, 0, w, srow, schunk);
#pragma unroll
    for (int q = 0; q < 4; ++q) stage_q(A, As, 0, q, row0, 0, w, srow, schunk);
    stage_q(A, As, 1, 0, row0, 64, w, srow, schunk);
    stage_q(A, As, 1, 2, row0, 64, w, srow, schunk);
#pragma unroll
    for (int q = 0; q < 4; ++q) stage_q(Bw, Bs, 1, q, col0, 64, w, srow, schunk);
    asm volatile("s_waitcnt vmcnt(6)" ::: "memory");  // seals buf0
    __builtin_amdgcn_s_barrier();

    for (int kt = 0; kt < NT; ++kt) {
        int buf = kt & 1, bn = buf ^ 1;
        int kc1 = (kt + 1) * 64, kc2 = (kt + 2) * 64;
        const char* AqL = (const char*)As + buf * 32768 + (2 * wr) * 8192 + lr * 128;
        const char* AqH = AqL + 8192;
        const char* Bq  = (const char*)Bs + buf * 32768 + wc * 8192 + lr * 128;

        // ===== P1 [mlo x nlo]: read a-lo(8) + b-lo(4); stage A-odd(kt+1) ====
#pragma unroll
        for (int mf = 0; mf < 4; ++mf) {
            a[mf]  = *(const bf16x8*)(AqL + mf * 2048 + o0);
            a2[mf] = *(const bf16x8*)(AqL + mf * 2048 + o1);
        }
#pragma unroll
        for (int nf = 0; nf < 2; ++nf) {
            blo[nf][0] = *(const bf16x8*)(Bq + nf * 2048 + o0);
            blo[nf][1] = *(const bf16x8*)(Bq + nf * 2048 + o1);
        }
        if (kt + 1 < NT) {
            stage_q(A, As, bn, 1, row0, kc1, w, srow, schunk);
            stage_q(A, As, bn, 3, row0, kc1, w, srow, schunk);
        }
        asm volatile("s_waitcnt lgkmcnt(8)" ::: "memory");
        PIN_PRE();
#pragma unroll
        for (int mf = 0; mf < 4; ++mf)
#pragma unroll
            for (int nf = 0; nf < 2; ++nf) {
                acc[mf][nf] = __builtin_amdgcn_mfma_f32_16x16x32_bf16(a[mf],  blo[nf][0], acc[mf][nf], 0, 0, 0);
                acc[mf][nf] = __builtin_amdgcn_mfma_f32_16x16x32_bf16(a2[mf], blo[nf][1], acc[mf][nf], 0, 0, 0);
            }
        PIN_POST();

        // ===== P2 [mlo x nhi]: read b-hi(4); stage A-even(kt+2) =============
#pragma unroll
        for (int nf = 0; nf < 2; ++nf) {
            bhi[nf][0] = *(const bf16x8*)(Bq + (2 + nf) * 2048 + o0);
            bhi[nf][1] = *(const bf16x8*)(Bq + (2 + nf) * 2048 + o1);
        }
        if (kt + 2 < NT) {
            stage_q(A, As, buf, 0, row0, kc2, w, srow, schunk);
            stage_q(A, As, buf, 2, row0, kc2, w, srow, schunk);
        }
        PIN_PRE();
#pragma unroll
        for (int mf = 0; mf < 4; ++mf)
#pragma unroll
            for (int nf = 0; nf < 2; ++nf) {
                acc[mf][2 + nf] = __builtin_amdgcn_mfma_f32_16x16x32_bf16(a[mf],  bhi[nf][0], acc[mf][2 + nf], 0, 0, 0);
                acc[mf][2 + nf] = __builtin_amdgcn_mfma_f32_16x16x32_bf16(a2[mf], bhi[nf][1], acc[mf][2 + nf], 0, 0, 0);
            }
        PIN_POST();

        // ===== P3 [mhi x nlo]: read a-hi(8); stage B01(kt+2) ================
#pragma unroll
        for (int mf = 0; mf < 4; ++mf) {
            a[mf]  = *(const bf16x8*)(AqH + mf * 2048 + o0);
            a2[mf] = *(const bf16x8*)(AqH + mf * 2048 + o1);
        }
        if (kt + 2 < NT) {
            stage_q(Bw, Bs, buf, 0, col0, kc2, w, srow, schunk);
            stage_q(Bw, Bs, buf, 1, col0, kc2, w, srow, schunk);
        }
        PIN_PRE();
#pragma unroll
        for (int mf = 0; mf < 4; ++mf)
#pragma unroll
            for (int nf = 0; nf < 2; ++nf) {
                acc[4 + mf][nf] = __builtin_amdgcn_mfma_f32_16x16x32_bf16(a[mf],  blo[nf][0], acc[4 + mf][nf], 0, 0, 0);
                acc[4 + mf][nf] = __builtin_amdgcn_mfma_f32_16x16x32_bf16(a2[mf], blo[nf][1], acc[4 + mf][nf], 0, 0, 0);
            }
        PIN_POST();

        // ===== P4 [mhi x nhi]: stage B23(kt+2); ONE vmcnt checkpoint ========
        if (kt + 2 < NT) {
            stage_q(Bw, Bs, buf, 2, col0, kc2, w, srow, schunk);
            stage_q(Bw, Bs, buf, 3, col0, kc2, w, srow, schunk);
        }
        if (kt + 2 < NT)      asm volatile("s_waitcnt vmcnt(6)" ::: "memory");
        else if (kt + 1 < NT) asm volatile("s_waitcnt vmcnt(0)" ::: "memory");
        __builtin_amdgcn_s_barrier();
        __builtin_amdgcn_s_setprio(1);
#pragma unroll
        for (int mf = 0; mf < 4; ++mf)
#pragma unroll
            for (int nf = 0; nf < 2; ++nf) {
                acc[4 + mf][2 + nf] = __builtin_amdgcn_mfma_f32_16x16x32_bf16(a[mf],  bhi[nf][0], acc[4 + mf][2 + nf], 0, 0, 0);
                acc[4 + mf][2 + nf] = __builtin_amdgcn_mfma_f32_16x16x32_bf16(a2[mf], bhi[nf][1], acc[4 + mf][2 + nf], 0, 0, 0);
            }
        PIN_POST();
    }

    // ---- MODE 1 (K): per-row sum-of-squares -> rnorm atomics (fp32 acc) ----
    if (MODE == 1) {
#pragma unroll
        for (int m = 0; m < 8; ++m)
#pragma unroll
            for (int j = 0; j < 4; ++j) {
                float s = acc[m][0][j] * acc[m][0][j] + acc[m][1][j] * acc[m][1][j]
                        + acc[m][2][j] * acc[m][2][j] + acc[m][3][j] * acc[m][3][j];
                s += __shfl_xor(s, 1); s += __shfl_xor(s, 2);
                s += __shfl_xor(s, 4); s += __shfl_xor(s, 8);
                if (lr == 0)
                    atomicAdd(&rnorm[row0 + wr * 128 + m * 16 + c16 * 4 + j], s);
            }
    }

    if (MODE != 2) {
        // ---- C tile -> SMEM, then coalesced 16B global stores --------------
#pragma unroll
        for (int m = 0; m < 8; ++m) {
            int lrow = wr * 128 + m * 16 + c16 * 4;
#pragma unroll
            for (int n = 0; n < 4; ++n) {
                int lcol = wc * 64 + n * 16 + lr;
#pragma unroll
                for (int j = 0; j < 4; ++j)
                    SMEM[(lrow + j) * 256 + lcol] = f2b(acc[m][n][j]);
            }
        }
        __syncthreads();
#pragma unroll
        for (int g = 0; g < 16; ++g) {
            int ch = g * 512 + t;           // 16B-chunk index in the 256x256 tile
            int r = ch >> 5, c8 = ch & 31;
            bf16x8 v = *(const bf16x8*)&SMEM[ch * 8];
            *(bf16x8*)&C[(size_t)(row0 + r) * 1024 + col0 + c8 * 8] = v;
        }
    } else {
        // ---- MODE 2 (V): register-sourced fused gf reduce -------------------
        float p[4] = {0.f, 0.f, 0.f, 0.f};
#pragma unroll
        for (int m = 0; m < 8; ++m)
#pragma unroll
            for (int j = 0; j < 4; ++j) {
                int r = wr * 128 + m * 16 + c16 * 4 + j;
                float inv = 1.0f / fmaxf(sqrtf(rnorm[row0 + r]), 1e-12f);
                const ushort* krow = &C[(size_t)(row0 + r) * 1024 + col0];
#pragma unroll
                for (int n = 0; n < 4; ++n)
                    p[n] += b2f(krow[wc * 64 + n * 16 + lr]) * inv * acc[m][n][j];
            }
#pragma unroll
        for (int n = 0; n < 4; ++n) {
            p[n] += __shfl_xor(p[n], 16);
            p[n] += __shfl_xor(p[n], 32);
        }
        float* part = (float*)SMEM;   // [8 waves][16 lr][4 n] = 2 KiB
        if (l < 16) {
#pragma unroll
            for (int n = 0; n < 4; ++n) part[(w * 16 + lr) * 4 + n] = p[n];
        }
        __syncthreads();
        if (t < 256) {
            int wcq = t >> 6, nq = (t >> 4) & 3, lrq = t & 15;
            float s = part[((wcq) * 16 + lrq) * 4 + nq]
                    + part[((4 + wcq) * 16 + lrq) * 4 + nq];
            int b = row0 >> 12;
            atomicAdd(&gf[b * 1024 + col0 + t], s * (1.0f / 4096.0f));
        }
    }
}

// ---------------- out[row,e] = l2norm(Q_pre)[row,e] * gf[b,e]  (fp32 out) ---
__global__ __launch_bounds__(256) void q_scale(const ushort* __restrict__ Qp,
                                               const float* __restrict__ gf,
                                               float* __restrict__ out) {
    const int D = 1024;
    int row = blockIdx.x * 4 + (threadIdx.x >> 6);
    int l = threadIdx.x & 63;
    int b = row >> 12;
    const ushort* qr = &Qp[(size_t)row * D];
    float qf[4][4];
    float ss = 0.f;
#pragma unroll
    for (int i = 0; i < 4; ++i) {
        ushort4 q = *(const ushort4*)&qr[l * 4 + i * 256];
        qf[i][0] = b2f(q.x); qf[i][1] = b2f(q.y);
        qf[i][2] = b2f(q.z); qf[i][3] = b2f(q.w);
        ss += qf[i][0] * qf[i][0] + qf[i][1] * qf[i][1] +
              qf[i][2] * qf[i][2] + qf[i][3] * qf[i][3];
    }
#pragma unroll
    for (int off = 32; off; off >>= 1) ss += __shfl_xor(ss, off);
    float inv = 1.0f / fmaxf(sqrtf(ss), 1e-12f);
#pragma unroll
    for (int i = 0; i < 4; ++i) {
        float4 g = *(const float4*)&gf[b * D + l * 4 + i * 256];
        float4 o;
        o.x = qf[i][0] * inv * g.x;
        o.y = qf[i][1] * inv * g.y;
        o.z = qf[i][2] * inv * g.z;
        o.w = qf[i][3] * inv * g.w;
        *(float4*)&out[(size_t)row * D + l * 4 + i * 256] = o;
    }
}

extern "C" void kernel_launch(void* const* d_in, const int* in_sizes, int n_in,
                              void* d_out, int out_size, void* d_ws, size_t ws_size,
                              hipStream_t stream) {
    const float* x  = (const float*)d_in[0];
    const float* Wq = (const float*)d_in[1];
    const float* Wk = (const float*)d_in[2];
    const float* Wv = (const float*)d_in[3];
    float* out = (float*)d_out;

    const int Bb = 8, Nn = 4096, D = 1024;
    const int M = Bb * Nn;  // 32768 rows

    char* ws = (char*)d_ws;
    ushort* xb  = (ushort*)ws;                         // 67108864 B
    ushort* wqb = (ushort*)(ws + 67108864);            // 2097152 B  } contiguous
    ushort* wkb = (ushort*)(ws + 69206016);            // 2097152 B  } bf16 W's
    ushort* wvb = (ushort*)(ws + 71303168);            // 2097152 B  }
    ushort* P1  = (ushort*)(ws + 73400320);            // 67108864 B (Q_pre)
    float*  gf  = (float*)(ws + 140509184);            // 32768 B

    // d_out (128 MB fp32): lower 64 MB = Kp (bf16), +64 MB = rnorm (128 KB).
    // Both dead before q_scale overwrites d_out with the final fp32 output.
    ushort* Kp = (ushort*)d_out;
    float* rnorm = (float*)((char*)d_out + 67108864);

    hipMemsetAsync(gf, 0, Bb * D * sizeof(float), stream);
    hipMemsetAsync(rnorm, 0, M * sizeof(float), stream);

    f2b_kernel<<<2048, 256, 0, stream>>>(x, xb, (M * D) / 4);
    f2b3_kernel<<<1536, 256, 0, stream>>>(Wq, Wk, Wv, wqb, (D * D) / 4);

    gemm_bt<1><<<512, 512, 0, stream>>>(xb, wkb, Kp, rnorm, nullptr);   // K + rnorm
    gemm_bt<2><<<512, 512, 0, stream>>>(xb, wvb, Kp, rnorm, gf);        // V -> gf
    gemm_bt<0><<<512, 512, 0, stream>>>(xb, wqb, P1, nullptr, nullptr); // Q
    q_scale<<<M / 4, 256, 0, stream>>>(P1, gf, out);
}

// Round 20
// 281.507 us; speedup vs baseline: 1.0971x; 1.0067x over previous
//
#include <hip/hip_runtime.h>

typedef __attribute__((ext_vector_type(4))) float f32x4;
typedef __attribute__((ext_vector_type(8))) short bf16x8;

#define AS1 __attribute__((address_space(1)))
#define AS3 __attribute__((address_space(3)))

static __device__ __forceinline__ ushort f2b(float f) {
    uint u = __float_as_uint(f);
    uint r = (u + 0x7fffu + ((u >> 16) & 1u)) >> 16;
    return (ushort)r;
}
static __device__ __forceinline__ float b2f(ushort h) {
    return __uint_as_float(((uint)h) << 16);
}

// ---- ALL fp32 inputs -> one contiguous bf16 stream (x | Wq | Wk | Wv) ------
// xb..wvb are contiguous in ws, so output index == global chunk index.
__global__ __launch_bounds__(256) void conv_all(const float* __restrict__ x,
                                                const float* __restrict__ Wq,
                                                const float* __restrict__ Wk,
                                                const float* __restrict__ Wv,
                                                ushort* __restrict__ out,
                                                int nx4, int nw4) {
    int i = blockIdx.x * blockDim.x + threadIdx.x;
    int stride = gridDim.x * blockDim.x;
    int ntot = nx4 + 3 * nw4;
    for (; i < ntot; i += stride) {
        const float* src;
        int j;
        if (i < nx4)               { src = x;  j = i; }
        else if (i < nx4 + nw4)    { src = Wq; j = i - nx4; }
        else if (i < nx4 + 2*nw4)  { src = Wk; j = i - nx4 - nw4; }
        else                       { src = Wv; j = i - nx4 - 2*nw4; }
        float4 v = ((const float4*)src)[j];
        ushort4 o;
        o.x = f2b(v.x); o.y = f2b(v.y); o.z = f2b(v.z); o.w = f2b(v.w);
        ((ushort4*)out)[i] = o;
    }
}

// ---------------- bf16 GEMM, C = A * B^T, 256x256, BK=64, 4-phase ----------
// R19 schedule with the explicit per-phase lgkmcnt(0) drain REMOVED: no
// ds_writes exist in the K-loop and global_load_lds visibility is ordered by
// the vmcnt seal (asm+"memory" fence) before the barrier, so the drain only
// covered same-wave read->MFMA deps — which the compiler handles with
// fine-grained lgkmcnt(N) per consumer. Dropping it lets early MFMAs overlap
// late ds_read latency. MODE: 0 = Q (plain C write), 1 = K (C write +
// per-row sum-of-squares atomics into rnorm), 2 = V (no C write; fused
// sum_n K*V/||K|| -> gf from fp32 accumulators, K re-read via L3).
__device__ __forceinline__ void stage_q(const ushort* __restrict__ G,
                                        ushort* Ls, int buf, int q, int rc0,
                                        int kcol, int w, int srow, int schunk) {
    ushort* dst = Ls + (buf * 4 + q) * 4096 + w * 512;  // wave-uniform base
    const ushort* src = G + (size_t)(rc0 + q * 64 + srow) * 1024 + kcol + schunk * 8;
    __builtin_amdgcn_global_load_lds((const AS1 void*)src, (AS3 void*)dst, 16, 0, 0);
}

#define PIN_PRE()  do { __builtin_amdgcn_s_barrier(); \
                        __builtin_amdgcn_s_setprio(1); } while (0)
#define PIN_POST() do { __builtin_amdgcn_s_setprio(0); \
                        __builtin_amdgcn_s_barrier(); } while (0)

template <int MODE>
__global__ __launch_bounds__(512, 2) void gemm_bt(const ushort* __restrict__ A,
                                                  const ushort* __restrict__ Bw,
                                                  ushort* __restrict__ C,
                                                  float* __restrict__ rnorm,
                                                  float* __restrict__ gf) {
    __shared__ ushort SMEM[65536];   // 128 KiB exactly: As | Bs
    ushort* As = SMEM;
    ushort* Bs = SMEM + 32768;

    // T1: XCD-chunked swizzle (nwg = 512)
    int nwg = gridDim.x, cpx = nwg >> 3, bid = blockIdx.x;
    int orig = (bid & 7) * cpx + (bid >> 3);
    int rt = orig >> 2, ct = orig & 3;
    int row0 = rt * 256, col0 = ct * 256;

    int t = threadIdx.x, l = t & 63, w = t >> 6;
    int wr = w >> 2, wc = w & 3;     // wave grid 2 (M) x 4 (N)
    int lr = l & 15, c16 = l >> 4;

    int srow = t >> 3;                     // staging row within quarter
    int schunk = (l & 7) ^ ((l >> 3) & 7); // staging source 16B chunk
    int o0 = ((c16 ^ (l & 7))) * 16;       // read slot bytes, k=0
    int o1 = o0 ^ 64;                      // k=1

    f32x4 acc[8][4] = {};
    bf16x8 a[4], a2[4], blo[2][2], bhi[2][2];

    const int NT = 16;  // K=1024 / 64
    // prologue: buf0 all 8 quarters; buf1: A-even (q0,q2) + B q0-3
#pragma unroll
    for (int q = 0; q < 4; ++q) stage_q(Bw, Bs, 0, q, col0, 0, w, srow, schunk);
#pragma unroll
    for (int q = 0; q < 4; ++q) stage_q(A, As, 0, q, row0, 0, w, srow, schunk);
    stage_q(A, As, 1, 0, row0, 64, w, srow, schunk);
    stage_q(A, As, 1, 2, row0, 64, w, srow, schunk);
#pragma unroll
    for (int q = 0; q < 4; ++q) stage_q(Bw, Bs, 1, q, col0, 64, w, srow, schunk);
    asm volatile("s_waitcnt vmcnt(6)" ::: "memory");  // seals buf0
    __builtin_amdgcn_s_barrier();

    for (int kt = 0; kt < NT; ++kt) {
        int buf = kt & 1, bn = buf ^ 1;
        int kc1 = (kt + 1) * 64, kc2 = (kt + 2) * 64;
        const char* AqL = (const char*)As + buf * 32768 + (2 * wr) * 8192 + lr * 128;
        const char* AqH = AqL + 8192;
        const char* Bq  = (const char*)Bs + buf * 32768 + wc * 8192 + lr * 128;

        // ===== P1 [mlo x nlo]: read a-lo(8) + b-lo(4); stage A-odd(kt+1) ====
#pragma unroll
        for (int mf = 0; mf < 4; ++mf) {
            a[mf]  = *(const bf16x8*)(AqL + mf * 2048 + o0);
            a2[mf] = *(const bf16x8*)(AqL + mf * 2048 + o1);
        }
#pragma unroll
        for (int nf = 0; nf < 2; ++nf) {
            blo[nf][0] = *(const bf16x8*)(Bq + nf * 2048 + o0);
            blo[nf][1] = *(const bf16x8*)(Bq + nf * 2048 + o1);
        }
        if (kt + 1 < NT) {
            stage_q(A, As, bn, 1, row0, kc1, w, srow, schunk);
            stage_q(A, As, bn, 3, row0, kc1, w, srow, schunk);
        }
        PIN_PRE();
#pragma unroll
        for (int mf = 0; mf < 4; ++mf)
#pragma unroll
            for (int nf = 0; nf < 2; ++nf) {
                acc[mf][nf] = __builtin_amdgcn_mfma_f32_16x16x32_bf16(a[mf],  blo[nf][0], acc[mf][nf], 0, 0, 0);
                acc[mf][nf] = __builtin_amdgcn_mfma_f32_16x16x32_bf16(a2[mf], blo[nf][1], acc[mf][nf], 0, 0, 0);
            }
        PIN_POST();

        // ===== P2 [mlo x nhi]: read b-hi(4); stage A-even(kt+2) =============
#pragma unroll
        for (int nf = 0; nf < 2; ++nf) {
            bhi[nf][0] = *(const bf16x8*)(Bq + (2 + nf) * 2048 + o0);
            bhi[nf][1] = *(const bf16x8*)(Bq + (2 + nf) * 2048 + o1);
        }
        if (kt + 2 < NT) {
            stage_q(A, As, buf, 0, row0, kc2, w, srow, schunk);
            stage_q(A, As, buf, 2, row0, kc2, w, srow, schunk);
        }
        PIN_PRE();
#pragma unroll
        for (int mf = 0; mf < 4; ++mf)
#pragma unroll
            for (int nf = 0; nf < 2; ++nf) {
                acc[mf][2 + nf] = __builtin_amdgcn_mfma_f32_16x16x32_bf16(a[mf],  bhi[nf][0], acc[mf][2 + nf], 0, 0, 0);
                acc[mf][2 + nf] = __builtin_amdgcn_mfma_f32_16x16x32_bf16(a2[mf], bhi[nf][1], acc[mf][2 + nf], 0, 0, 0);
            }
        PIN_POST();

        // ===== P3 [mhi x nlo]: read a-hi(8); stage B01(kt+2) ================
#pragma unroll
        for (int mf = 0; mf < 4; ++mf) {
            a[mf]  = *(const bf16x8*)(AqH + mf * 2048 + o0);
            a2[mf] = *(const bf16x8*)(AqH + mf * 2048 + o1);
        }
        if (kt + 2 < NT) {
            stage_q(Bw, Bs, buf, 0, col0, kc2, w, srow, schunk);
            stage_q(Bw, Bs, buf, 1, col0, kc2, w, srow, schunk);
        }
        PIN_PRE();
#pragma unroll
        for (int mf = 0; mf < 4; ++mf)
#pragma unroll
            for (int nf = 0; nf < 2; ++nf) {
                acc[4 + mf][nf] = __builtin_amdgcn_mfma_f32_16x16x32_bf16(a[mf],  blo[nf][0], acc[4 + mf][nf], 0, 0, 0);
                acc[4 + mf][nf] = __builtin_amdgcn_mfma_f32_16x16x32_bf16(a2[mf], blo[nf][1], acc[4 + mf][nf], 0, 0, 0);
            }
        PIN_POST();

        // ===== P4 [mhi x nhi]: stage B23(kt+2); ONE vmcnt checkpoint ========
        if (kt + 2 < NT) {
            stage_q(Bw, Bs, buf, 2, col0, kc2, w, srow, schunk);
            stage_q(Bw, Bs, buf, 3, col0, kc2, w, srow, schunk);
        }
        if (kt + 2 < NT)      asm volatile("s_waitcnt vmcnt(6)" ::: "memory");
        else if (kt + 1 < NT) asm volatile("s_waitcnt vmcnt(0)" ::: "memory");
        __builtin_amdgcn_s_barrier();
        __builtin_amdgcn_s_setprio(1);
#pragma unroll
        for (int mf = 0; mf < 4; ++mf)
#pragma unroll
            for (int nf = 0; nf < 2; ++nf) {
                acc[4 + mf][2 + nf] = __builtin_amdgcn_mfma_f32_16x16x32_bf16(a[mf],  bhi[nf][0], acc[4 + mf][2 + nf], 0, 0, 0);
                acc[4 + mf][2 + nf] = __builtin_amdgcn_mfma_f32_16x16x32_bf16(a2[mf], bhi[nf][1], acc[4 + mf][2 + nf], 0, 0, 0);
            }
        PIN_POST();
    }

    // ---- MODE 1 (K): per-row sum-of-squares -> rnorm atomics (fp32 acc) ----
    if (MODE == 1) {
#pragma unroll
        for (int m = 0; m < 8; ++m)
#pragma unroll
            for (int j = 0; j < 4; ++j) {
                float s = acc[m][0][j] * acc[m][0][j] + acc[m][1][j] * acc[m][1][j]
                        + acc[m][2][j] * acc[m][2][j] + acc[m][3][j] * acc[m][3][j];
                s += __shfl_xor(s, 1); s += __shfl_xor(s, 2);
                s += __shfl_xor(s, 4); s += __shfl_xor(s, 8);
                if (lr == 0)
                    atomicAdd(&rnorm[row0 + wr * 128 + m * 16 + c16 * 4 + j], s);
            }
    }

    if (MODE != 2) {
        // ---- C tile -> SMEM, then coalesced 16B global stores --------------
#pragma unroll
        for (int m = 0; m < 8; ++m) {
            int lrow = wr * 128 + m * 16 + c16 * 4;
#pragma unroll
            for (int n = 0; n < 4; ++n) {
                int lcol = wc * 64 + n * 16 + lr;
#pragma unroll
                for (int j = 0; j < 4; ++j)
                    SMEM[(lrow + j) * 256 + lcol] = f2b(acc[m][n][j]);
            }
        }
        __syncthreads();
#pragma unroll
        for (int g = 0; g < 16; ++g) {
            int ch = g * 512 + t;           // 16B-chunk index in the 256x256 tile
            int r = ch >> 5, c8 = ch & 31;
            bf16x8 v = *(const bf16x8*)&SMEM[ch * 8];
            *(bf16x8*)&C[(size_t)(row0 + r) * 1024 + col0 + c8 * 8] = v;
        }
    } else {
        // ---- MODE 2 (V): register-sourced fused gf reduce -------------------
        float p[4] = {0.f, 0.f, 0.f, 0.f};
#pragma unroll
        for (int m = 0; m < 8; ++m)
#pragma unroll
            for (int j = 0; j < 4; ++j) {
                int r = wr * 128 + m * 16 + c16 * 4 + j;
                float inv = 1.0f / fmaxf(sqrtf(rnorm[row0 + r]), 1e-12f);
                const ushort* krow = &C[(size_t)(row0 + r) * 1024 + col0];
#pragma unroll
                for (int n = 0; n < 4; ++n)
                    p[n] += b2f(krow[wc * 64 + n * 16 + lr]) * inv * acc[m][n][j];
            }
#pragma unroll
        for (int n = 0; n < 4; ++n) {
            p[n] += __shfl_xor(p[n], 16);
            p[n] += __shfl_xor(p[n], 32);
        }
        float* part = (float*)SMEM;   // [8 waves][16 lr][4 n] = 2 KiB
        if (l < 16) {
#pragma unroll
            for (int n = 0; n < 4; ++n) part[(w * 16 + lr) * 4 + n] = p[n];
        }
        __syncthreads();
        if (t < 256) {
            int wcq = t >> 6, nq = (t >> 4) & 3, lrq = t & 15;
            float s = part[((wcq) * 16 + lrq) * 4 + nq]
                    + part[((4 + wcq) * 16 + lrq) * 4 + nq];
            int b = row0 >> 12;
            atomicAdd(&gf[b * 1024 + col0 + t], s * (1.0f / 4096.0f));
        }
    }
}

// ---------------- out[row,e] = l2norm(Q_pre)[row,e] * gf[b,e]  (fp32 out) ---
__global__ __launch_bounds__(256) void q_scale(const ushort* __restrict__ Qp,
                                               const float* __restrict__ gf,
                                               float* __restrict__ out) {
    const int D = 1024;
    int row = blockIdx.x * 4 + (threadIdx.x >> 6);
    int l = threadIdx.x & 63;
    int b = row >> 12;
    const ushort* qr = &Qp[(size_t)row * D];
    float qf[4][4];
    float ss = 0.f;
#pragma unroll
    for (int i = 0; i < 4; ++i) {
        ushort4 q = *(const ushort4*)&qr[l * 4 + i * 256];
        qf[i][0] = b2f(q.x); qf[i][1] = b2f(q.y);
        qf[i][2] = b2f(q.z); qf[i][3] = b2f(q.w);
        ss += qf[i][0] * qf[i][0] + qf[i][1] * qf[i][1] +
              qf[i][2] * qf[i][2] + qf[i][3] * qf[i][3];
    }
#pragma unroll
    for (int off = 32; off; off >>= 1) ss += __shfl_xor(ss, off);
    float inv = 1.0f / fmaxf(sqrtf(ss), 1e-12f);
#pragma unroll
    for (int i = 0; i < 4; ++i) {
        float4 g = *(const float4*)&gf[b * D + l * 4 + i * 256];
        float4 o;
        o.x = qf[i][0] * inv * g.x;
        o.y = qf[i][1] * inv * g.y;
        o.z = qf[i][2] * inv * g.z;
        o.w = qf[i][3] * inv * g.w;
        *(float4*)&out[(size_t)row * D + l * 4 + i * 256] = o;
    }
}

extern "C" void kernel_launch(void* const* d_in, const int* in_sizes, int n_in,
                              void* d_out, int out_size, void* d_ws, size_t ws_size,
                              hipStream_t stream) {
    const float* x  = (const float*)d_in[0];
    const float* Wq = (const float*)d_in[1];
    const float* Wk = (const float*)d_in[2];
    const float* Wv = (const float*)d_in[3];
    float* out = (float*)d_out;

    const int Bb = 8, Nn = 4096, D = 1024;
    const int M = Bb * Nn;  // 32768 rows

    char* ws = (char*)d_ws;
    ushort* xb  = (ushort*)ws;                         // 67108864 B } contiguous
    ushort* wqb = (ushort*)(ws + 67108864);            // 2097152 B  } bf16
    ushort* wkb = (ushort*)(ws + 69206016);            // 2097152 B  } output
    ushort* wvb = (ushort*)(ws + 71303168);            // 2097152 B  } stream
    ushort* P1  = (ushort*)(ws + 73400320);            // 67108864 B (Q_pre)
    float*  gf  = (float*)(ws + 140509184);            // 32768 B

    // d_out (128 MB fp32): lower 64 MB = Kp (bf16), +64 MB = rnorm (128 KB).
    // Both dead before q_scale overwrites d_out with the final fp32 output.
    ushort* Kp = (ushort*)d_out;
    float* rnorm = (float*)((char*)d_out + 67108864);

    hipMemsetAsync(gf, 0, Bb * D * sizeof(float), stream);
    hipMemsetAsync(rnorm, 0, M * sizeof(float), stream);

    conv_all<<<2048, 256, 0, stream>>>(x, Wq, Wk, Wv, xb,
                                       (M * D) / 4, (D * D) / 4);

    gemm_bt<1><<<512, 512, 0, stream>>>(xb, wkb, Kp, rnorm, nullptr);   // K + rnorm
    gemm_bt<2><<<512, 512, 0, stream>>>(xb, wvb, Kp, rnorm, gf);        // V -> gf
    gemm_bt<0><<<512, 512, 0, stream>>>(xb, wqb, P1, nullptr, nullptr); // Q
    q_scale<<<M / 4, 256, 0, stream>>>(P1, gf, out);
}

// Round 21
// 275.454 us; speedup vs baseline: 1.1212x; 1.0220x over previous
//
#include <hip/hip_runtime.h>

typedef __attribute__((ext_vector_type(4))) float f32x4;
typedef __attribute__((ext_vector_type(8))) short bf16x8;

#define AS1 __attribute__((address_space(1)))
#define AS3 __attribute__((address_space(3)))

static __device__ __forceinline__ ushort f2b(float f) {
    uint u = __float_as_uint(f);
    uint r = (u + 0x7fffu + ((u >> 16) & 1u)) >> 16;
    return (ushort)r;
}
static __device__ __forceinline__ float b2f(ushort h) {
    return __uint_as_float(((uint)h) << 16);
}

// ---- ALL fp32 inputs -> one contiguous bf16 stream (x | Wq | Wk | Wv),
//      PLUS zero-init of gf (2048 float4) and rnorm (8192 float4) ----------
__global__ __launch_bounds__(256) void conv_all(const float* __restrict__ x,
                                                const float* __restrict__ Wq,
                                                const float* __restrict__ Wk,
                                                const float* __restrict__ Wv,
                                                ushort* __restrict__ out,
                                                float* __restrict__ gf,
                                                float* __restrict__ rnorm,
                                                int nx4, int nw4) {
    int i = blockIdx.x * blockDim.x + threadIdx.x;
    int stride = gridDim.x * blockDim.x;
    int nconv = nx4 + 3 * nw4;
    int ntot = nconv + 2048 + 8192;
    for (; i < ntot; i += stride) {
        if (i < nconv) {
            const float* src;
            int j;
            if (i < nx4)              { src = x;  j = i; }
            else if (i < nx4 + nw4)   { src = Wq; j = i - nx4; }
            else if (i < nx4 + 2*nw4) { src = Wk; j = i - nx4 - nw4; }
            else                      { src = Wv; j = i - nx4 - 2*nw4; }
            float4 v = ((const float4*)src)[j];
            ushort4 o;
            o.x = f2b(v.x); o.y = f2b(v.y); o.z = f2b(v.z); o.w = f2b(v.w);
            ((ushort4*)out)[i] = o;
        } else if (i < nconv + 2048) {
            float4 z = {0.f, 0.f, 0.f, 0.f};
            ((float4*)gf)[i - nconv] = z;
        } else {
            float4 z = {0.f, 0.f, 0.f, 0.f};
            ((float4*)rnorm)[i - nconv - 2048] = z;
        }
    }
}

// ---------------- bf16 GEMM, C = A * B^T, 256x256, BK=64, 4-phase ----------
// Proven schedule (R13/R19/R20): deep staging (stage kt+1 A-odd @P1, kt+2
// A-even @P2, kt+2 B @P3/P4), ONE vmcnt(6) checkpoint per K-tile, barrier +
// setprio phase boundaries (no explicit lgkm drain — compiler emits
// fine-grained lgkmcnt per consumer; global_load_lds visibility ordered by
// the vmcnt seal before the barrier). SMEM exactly 128 KiB (R14 lesson).
// MODE: 0 = Q (plain C write), 1 = K (C write + per-row sum-of-squares
// atomics into rnorm), 2 = V (no C write; fused sum_n K*V/||K|| -> gf from
// fp32 accumulators, K re-read via L3).
__device__ __forceinline__ void stage_q(const ushort* __restrict__ G,
                                        ushort* Ls, int buf, int q, int rc0,
                                        int kcol, int w, int srow, int schunk) {
    ushort* dst = Ls + (buf * 4 + q) * 4096 + w * 512;  // wave-uniform base
    const ushort* src = G + (size_t)(rc0 + q * 64 + srow) * 1024 + kcol + schunk * 8;
    __builtin_amdgcn_global_load_lds((const AS1 void*)src, (AS3 void*)dst, 16, 0, 0);
}

#define PIN_PRE()  do { __builtin_amdgcn_s_barrier(); \
                        __builtin_amdgcn_s_setprio(1); } while (0)
#define PIN_POST() do { __builtin_amdgcn_s_setprio(0); \
                        __builtin_amdgcn_s_barrier(); } while (0)

template <int MODE>
__global__ __launch_bounds__(512, 2) void gemm_bt(const ushort* __restrict__ A,
                                                  const ushort* __restrict__ Bw,
                                                  ushort* __restrict__ C,
                                                  float* __restrict__ rnorm,
                                                  float* __restrict__ gf) {
    __shared__ ushort SMEM[65536];   // 128 KiB exactly: As | Bs
    ushort* As = SMEM;
    ushort* Bs = SMEM + 32768;

    // T1: XCD-chunked swizzle (nwg = 512)
    int nwg = gridDim.x, cpx = nwg >> 3, bid = blockIdx.x;
    int orig = (bid & 7) * cpx + (bid >> 3);
    int rt = orig >> 2, ct = orig & 3;
    int row0 = rt * 256, col0 = ct * 256;

    int t = threadIdx.x, l = t & 63, w = t >> 6;
    int wr = w >> 2, wc = w & 3;     // wave grid 2 (M) x 4 (N)
    int lr = l & 15, c16 = l >> 4;

    int srow = t >> 3;                     // staging row within quarter
    int schunk = (l & 7) ^ ((l >> 3) & 7); // staging source 16B chunk
    int o0 = ((c16 ^ (l & 7))) * 16;       // read slot bytes, k=0
    int o1 = o0 ^ 64;                      // k=1

    f32x4 acc[8][4] = {};
    bf16x8 a[4], a2[4], blo[2][2], bhi[2][2];

    const int NT = 16;  // K=1024 / 64
    // prologue: buf0 all 8 quarters; buf1: A-even (q0,q2) + B q0-3
#pragma unroll
    for (int q = 0; q < 4; ++q) stage_q(Bw, Bs, 0, q, col0, 0, w, srow, schunk);
#pragma unroll
    for (int q = 0; q < 4; ++q) stage_q(A, As, 0, q, row0, 0, w, srow, schunk);
    stage_q(A, As, 1, 0, row0, 64, w, srow, schunk);
    stage_q(A, As, 1, 2, row0, 64, w, srow, schunk);
#pragma unroll
    for (int q = 0; q < 4; ++q) stage_q(Bw, Bs, 1, q, col0, 64, w, srow, schunk);
    asm volatile("s_waitcnt vmcnt(6)" ::: "memory");  // seals buf0
    __builtin_amdgcn_s_barrier();

    for (int kt = 0; kt < NT; ++kt) {
        int buf = kt & 1, bn = buf ^ 1;
        int kc1 = (kt + 1) * 64, kc2 = (kt + 2) * 64;
        const char* AqL = (const char*)As + buf * 32768 + (2 * wr) * 8192 + lr * 128;
        const char* AqH = AqL + 8192;
        const char* Bq  = (const char*)Bs + buf * 32768 + wc * 8192 + lr * 128;

        // ===== P1 [mlo x nlo]: read a-lo(8) + b-lo(4); stage A-odd(kt+1) ====
#pragma unroll
        for (int mf = 0; mf < 4; ++mf) {
            a[mf]  = *(const bf16x8*)(AqL + mf * 2048 + o0);
            a2[mf] = *(const bf16x8*)(AqL + mf * 2048 + o1);
        }
#pragma unroll
        for (int nf = 0; nf < 2; ++nf) {
            blo[nf][0] = *(const bf16x8*)(Bq + nf * 2048 + o0);
            blo[nf][1] = *(const bf16x8*)(Bq + nf * 2048 + o1);
        }
        if (kt + 1 < NT) {
            stage_q(A, As, bn, 1, row0, kc1, w, srow, schunk);
            stage_q(A, As, bn, 3, row0, kc1, w, srow, schunk);
        }
        PIN_PRE();
#pragma unroll
        for (int mf = 0; mf < 4; ++mf)
#pragma unroll
            for (int nf = 0; nf < 2; ++nf) {
                acc[mf][nf] = __builtin_amdgcn_mfma_f32_16x16x32_bf16(a[mf],  blo[nf][0], acc[mf][nf], 0, 0, 0);
                acc[mf][nf] = __builtin_amdgcn_mfma_f32_16x16x32_bf16(a2[mf], blo[nf][1], acc[mf][nf], 0, 0, 0);
            }
        PIN_POST();

        // ===== P2 [mlo x nhi]: read b-hi(4); stage A-even(kt+2) =============
#pragma unroll
        for (int nf = 0; nf < 2; ++nf) {
            bhi[nf][0] = *(const bf16x8*)(Bq + (2 + nf) * 2048 + o0);
            bhi[nf][1] = *(const bf16x8*)(Bq + (2 + nf) * 2048 + o1);
        }
        if (kt + 2 < NT) {
            stage_q(A, As, buf, 0, row0, kc2, w, srow, schunk);
            stage_q(A, As, buf, 2, row0, kc2, w, srow, schunk);
        }
        PIN_PRE();
#pragma unroll
        for (int mf = 0; mf < 4; ++mf)
#pragma unroll
            for (int nf = 0; nf < 2; ++nf) {
                acc[mf][2 + nf] = __builtin_amdgcn_mfma_f32_16x16x32_bf16(a[mf],  bhi[nf][0], acc[mf][2 + nf], 0, 0, 0);
                acc[mf][2 + nf] = __builtin_amdgcn_mfma_f32_16x16x32_bf16(a2[mf], bhi[nf][1], acc[mf][2 + nf], 0, 0, 0);
            }
        PIN_POST();

        // ===== P3 [mhi x nlo]: read a-hi(8); stage B01(kt+2) ================
#pragma unroll
        for (int mf = 0; mf < 4; ++mf) {
            a[mf]  = *(const bf16x8*)(AqH + mf * 2048 + o0);
            a2[mf] = *(const bf16x8*)(AqH + mf * 2048 + o1);
        }
        if (kt + 2 < NT) {
            stage_q(Bw, Bs, buf, 0, col0, kc2, w, srow, schunk);
            stage_q(Bw, Bs, buf, 1, col0, kc2, w, srow, schunk);
        }
        PIN_PRE();
#pragma unroll
        for (int mf = 0; mf < 4; ++mf)
#pragma unroll
            for (int nf = 0; nf < 2; ++nf) {
                acc[4 + mf][nf] = __builtin_amdgcn_mfma_f32_16x16x32_bf16(a[mf],  blo[nf][0], acc[4 + mf][nf], 0, 0, 0);
                acc[4 + mf][nf] = __builtin_amdgcn_mfma_f32_16x16x32_bf16(a2[mf], blo[nf][1], acc[4 + mf][nf], 0, 0, 0);
            }
        PIN_POST();

        // ===== P4 [mhi x nhi]: stage B23(kt+2); ONE vmcnt checkpoint ========
        if (kt + 2 < NT) {
            stage_q(Bw, Bs, buf, 2, col0, kc2, w, srow, schunk);
            stage_q(Bw, Bs, buf, 3, col0, kc2, w, srow, schunk);
        }
        if (kt + 2 < NT)      asm volatile("s_waitcnt vmcnt(6)" ::: "memory");
        else if (kt + 1 < NT) asm volatile("s_waitcnt vmcnt(0)" ::: "memory");
        __builtin_amdgcn_s_barrier();
        __builtin_amdgcn_s_setprio(1);
#pragma unroll
        for (int mf = 0; mf < 4; ++mf)
#pragma unroll
            for (int nf = 0; nf < 2; ++nf) {
                acc[4 + mf][2 + nf] = __builtin_amdgcn_mfma_f32_16x16x32_bf16(a[mf],  bhi[nf][0], acc[4 + mf][2 + nf], 0, 0, 0);
                acc[4 + mf][2 + nf] = __builtin_amdgcn_mfma_f32_16x16x32_bf16(a2[mf], bhi[nf][1], acc[4 + mf][2 + nf], 0, 0, 0);
            }
        PIN_POST();
    }

    // ---- MODE 1 (K): per-row sum-of-squares -> rnorm atomics (fp32 acc) ----
    if (MODE == 1) {
#pragma unroll
        for (int m = 0; m < 8; ++m)
#pragma unroll
            for (int j = 0; j < 4; ++j) {
                float s = acc[m][0][j] * acc[m][0][j] + acc[m][1][j] * acc[m][1][j]
                        + acc[m][2][j] * acc[m][2][j] + acc[m][3][j] * acc[m][3][j];
                s += __shfl_xor(s, 1); s += __shfl_xor(s, 2);
                s += __shfl_xor(s, 4); s += __shfl_xor(s, 8);
                if (lr == 0)
                    atomicAdd(&rnorm[row0 + wr * 128 + m * 16 + c16 * 4 + j], s);
            }
    }

    if (MODE != 2) {
        // ---- C tile -> SMEM, then coalesced 16B global stores --------------
#pragma unroll
        for (int m = 0; m < 8; ++m) {
            int lrow = wr * 128 + m * 16 + c16 * 4;
#pragma unroll
            for (int n = 0; n < 4; ++n) {
                int lcol = wc * 64 + n * 16 + lr;
#pragma unroll
                for (int j = 0; j < 4; ++j)
                    SMEM[(lrow + j) * 256 + lcol] = f2b(acc[m][n][j]);
            }
        }
        __syncthreads();
#pragma unroll
        for (int g = 0; g < 16; ++g) {
            int ch = g * 512 + t;           // 16B-chunk index in the 256x256 tile
            int r = ch >> 5, c8 = ch & 31;
            bf16x8 v = *(const bf16x8*)&SMEM[ch * 8];
            *(bf16x8*)&C[(size_t)(row0 + r) * 1024 + col0 + c8 * 8] = v;
        }
    } else {
        // ---- MODE 2 (V): register-sourced fused gf reduce -------------------
        float p[4] = {0.f, 0.f, 0.f, 0.f};
#pragma unroll
        for (int m = 0; m < 8; ++m)
#pragma unroll
            for (int j = 0; j < 4; ++j) {
                int r = wr * 128 + m * 16 + c16 * 4 + j;
                float inv = 1.0f / fmaxf(sqrtf(rnorm[row0 + r]), 1e-12f);
                const ushort* krow = &C[(size_t)(row0 + r) * 1024 + col0];
#pragma unroll
                for (int n = 0; n < 4; ++n)
                    p[n] += b2f(krow[wc * 64 + n * 16 + lr]) * inv * acc[m][n][j];
            }
#pragma unroll
        for (int n = 0; n < 4; ++n) {
            p[n] += __shfl_xor(p[n], 16);
            p[n] += __shfl_xor(p[n], 32);
        }
        float* part = (float*)SMEM;   // [8 waves][16 lr][4 n] = 2 KiB
        if (l < 16) {
#pragma unroll
            for (int n = 0; n < 4; ++n) part[(w * 16 + lr) * 4 + n] = p[n];
        }
        __syncthreads();
        if (t < 256) {
            int wcq = t >> 6, nq = (t >> 4) & 3, lrq = t & 15;
            float s = part[((wcq) * 16 + lrq) * 4 + nq]
                    + part[((4 + wcq) * 16 + lrq) * 4 + nq];
            int b = row0 >> 12;
            atomicAdd(&gf[b * 1024 + col0 + t], s * (1.0f / 4096.0f));
        }
    }
}

// ---------------- out[row,e] = l2norm(Q_pre)[row,e] * gf[b,e]  (fp32 out) ---
__global__ __launch_bounds__(256) void q_scale(const ushort* __restrict__ Qp,
                                               const float* __restrict__ gf,
                                               float* __restrict__ out) {
    const int D = 1024;
    int row = blockIdx.x * 4 + (threadIdx.x >> 6);
    int l = threadIdx.x & 63;
    int b = row >> 12;
    const ushort* qr = &Qp[(size_t)row * D];
    float qf[4][4];
    float ss = 0.f;
#pragma unroll
    for (int i = 0; i < 4; ++i) {
        ushort4 q = *(const ushort4*)&qr[l * 4 + i * 256];
        qf[i][0] = b2f(q.x); qf[i][1] = b2f(q.y);
        qf[i][2] = b2f(q.z); qf[i][3] = b2f(q.w);
        ss += qf[i][0] * qf[i][0] + qf[i][1] * qf[i][1] +
              qf[i][2] * qf[i][2] + qf[i][3] * qf[i][3];
    }
#pragma unroll
    for (int off = 32; off; off >>= 1) ss += __shfl_xor(ss, off);
    float inv = 1.0f / fmaxf(sqrtf(ss), 1e-12f);
#pragma unroll
    for (int i = 0; i < 4; ++i) {
        float4 g = *(const float4*)&gf[b * D + l * 4 + i * 256];
        float4 o;
        o.x = qf[i][0] * inv * g.x;
        o.y = qf[i][1] * inv * g.y;
        o.z = qf[i][2] * inv * g.z;
        o.w = qf[i][3] * inv * g.w;
        *(float4*)&out[(size_t)row * D + l * 4 + i * 256] = o;
    }
}

extern "C" void kernel_launch(void* const* d_in, const int* in_sizes, int n_in,
                              void* d_out, int out_size, void* d_ws, size_t ws_size,
                              hipStream_t stream) {
    const float* x  = (const float*)d_in[0];
    const float* Wq = (const float*)d_in[1];
    const float* Wk = (const float*)d_in[2];
    const float* Wv = (const float*)d_in[3];
    float* out = (float*)d_out;

    const int Bb = 8, Nn = 4096, D = 1024;
    const int M = Bb * Nn;  // 32768 rows

    char* ws = (char*)d_ws;
    ushort* xb  = (ushort*)ws;                         // 67108864 B } contiguous
    ushort* wqb = (ushort*)(ws + 67108864);            // 2097152 B  } bf16
    ushort* wkb = (ushort*)(ws + 69206016);            // 2097152 B  } output
    ushort* wvb = (ushort*)(ws + 71303168);            // 2097152 B  } stream
    ushort* P1  = (ushort*)(ws + 73400320);            // 67108864 B (Q_pre)
    float*  gf  = (float*)(ws + 140509184);            // 32768 B

    // d_out (128 MB fp32): lower 64 MB = Kp (bf16), +64 MB = rnorm (128 KB).
    // Both dead before q_scale overwrites d_out with the final fp32 output.
    ushort* Kp = (ushort*)d_out;
    float* rnorm = (float*)((char*)d_out + 67108864);

    conv_all<<<2048, 256, 0, stream>>>(x, Wq, Wk, Wv, xb, gf, rnorm,
                                       (M * D) / 4, (D * D) / 4);

    gemm_bt<1><<<512, 512, 0, stream>>>(xb, wkb, Kp, rnorm, nullptr);   // K + rnorm
    gemm_bt<2><<<512, 512, 0, stream>>>(xb, wvb, Kp, rnorm, gf);        // V -> gf
    gemm_bt<0><<<512, 512, 0, stream>>>(xb, wqb, P1, nullptr, nullptr); // Q
    q_scale<<<M / 4, 256, 0, stream>>>(P1, gf, out);
}